// Round 13
// baseline (125.078 us; speedup 1.0000x reference)
//
#include <hip/hip_runtime.h>
#include <hip/hip_bf16.h>
#include <math.h>

#define BATCH  4
#define SEQ    2048
#define DMODEL 256
#define NH     8
#define DH     32
#define MTOT   (BATCH*SEQ)   // 8192
// Q is pre-scaled by 256^-0.5 * log2(e) so attention uses p = exp2(q.k) raw.
#define QSCALE 0.09016844005556021f

typedef short  bf16x8 __attribute__((ext_vector_type(8)));
typedef float  f32x4  __attribute__((ext_vector_type(4)));

static __device__ __forceinline__ ushort f2bf(float f) {
    __hip_bfloat16 h = __float2bfloat16(f);
    return __builtin_bit_cast(ushort, h);
}
static __device__ __forceinline__ uint rne2(float a, float b) {
    uint ua = __builtin_bit_cast(uint, a);
    uint ub = __builtin_bit_cast(uint, b);
    ua += 0x7FFFu + ((ua >> 16) & 1u);
    ub += 0x7FFFu + ((ub >> 16) & 1u);
    return __builtin_amdgcn_perm(ub, ua, 0x07060302);
}
static __device__ __forceinline__ uint pk2(float a, float b) {
#if __has_builtin(__builtin_amdgcn_cvt_pk_bf16_f32)
    auto r = __builtin_amdgcn_cvt_pk_bf16_f32(a, b);
    return __builtin_bit_cast(uint, r);
#else
    return rne2(a, b);
#endif
}

#define LSQ 72       // qkv/out LDS row stride (64 + 8 pad), ushorts
#define KS_STRIDE 40
#define VT_STRIDE 136
#define P2_STRIDE 72   // two-pass P: 64 cols + 8 pad

// ---------------------------------------------------------------------------
// Kernel 0: weight transposes + x fp32->bf16 conversion. (r8/r11, proven)
// ---------------------------------------------------------------------------
__global__ __launch_bounds__(256) void wcvt_all(
    const float* __restrict__ wq, const float* __restrict__ wo,
    const float* __restrict__ x,
    ushort* __restrict__ wqT, ushort* __restrict__ woT,
    ushort* __restrict__ xbf)
{
    const int t  = threadIdx.x;
    const int bx = blockIdx.x;
    if (bx >= 32) {
        const size_t base = ((size_t)(bx - 32) * 8 + blockIdx.y) * 4096 + t * 16;
        float4 f0 = *(const float4*)(x + base);
        float4 f1 = *(const float4*)(x + base + 4);
        float4 f2 = *(const float4*)(x + base + 8);
        float4 f3 = *(const float4*)(x + base + 12);
        uint4 w0, w1;
        w0.x = pk2(f0.x, f0.y); w0.y = pk2(f0.z, f0.w);
        w0.z = pk2(f1.x, f1.y); w0.w = pk2(f1.z, f1.w);
        w1.x = pk2(f2.x, f2.y); w1.y = pk2(f2.z, f2.w);
        w1.z = pk2(f3.x, f3.y); w1.w = pk2(f3.z, f3.w);
        *(uint4*)&xbf[base]     = w0;
        *(uint4*)&xbf[base + 8] = w1;
        return;
    }
    __shared__ float T[32][33];
    const float* w; ushort* wT; int N, n0;
    if (bx < 24) { w = wq; wT = wqT; N = 768; n0 = bx * 32; }
    else         { w = wo; wT = woT; N = 256; n0 = (bx - 24) * 32; }
    const int k0 = blockIdx.y * 32;
    {
        int tr = t >> 3, tc = (t & 7) * 4;
        *(float4*)&T[tr][tc] = *(const float4*)(w + (size_t)(k0 + tr) * N + n0 + tc);
    }
    __syncthreads();
    int nl = t >> 3, kq = (t & 7) * 4;
    ushort4 pk;
    pk.x = f2bf(T[kq + 0][nl]); pk.y = f2bf(T[kq + 1][nl]);
    pk.z = f2bf(T[kq + 2][nl]); pk.w = f2bf(T[kq + 3][nl]);
    *(ushort4*)&wT[(size_t)(n0 + nl) * 256 + k0 + kq] = pk;
}

// ---------------------------------------------------------------------------
// Kernel 1: QKV projection, bf16 MFMA, scalar reg-prefetch. (r8, proven)
// ---------------------------------------------------------------------------
__global__ __launch_bounds__(256, 3) void qkv_gemm(
    const ushort* __restrict__ xb_, const ushort* __restrict__ wT,
    const float* __restrict__ bias,
    ushort* __restrict__ qo, ushort* __restrict__ ko, ushort* __restrict__ vo)
{
    __shared__ ushort As[64 * LSQ];
    __shared__ ushort Bs[128 * LSQ];
    const int tid  = threadIdx.x;
    const int wid  = tid >> 6;
    const int lane = tid & 63;
    const int lq   = lane & 15;
    const int quad = lane >> 4;
    const int wm   = wid & 1;
    const int wn   = wid >> 1;
    const int m0   = blockIdx.y * 64;
    const int n0   = blockIdx.x * 128;
    const bool isV = (blockIdx.x >= 4);

    const int ar0 = tid >> 3,         ac0 = (tid & 7) * 8;
    const int ar1 = (tid + 256) >> 3;
    const int br0 = tid >> 3,         bc0 = (tid & 7) * 8;
    const int br1 = (tid + 256) >> 3;
    const int br2 = (tid + 512) >> 3;
    const int br3 = (tid + 768) >> 3;

    const ushort* xb = xb_ + (size_t)m0 * 256;
    const ushort* wb = wT  + (size_t)n0 * 256;

    f32x4 acc[8];
#pragma unroll
    for (int i = 0; i < 8; ++i) acc[i] = {0.f, 0.f, 0.f, 0.f};

    uint4 ra0 = *(const uint4*)(xb + (size_t)ar0 * 256 + ac0);
    uint4 ra1 = *(const uint4*)(xb + (size_t)ar1 * 256 + ac0);
    uint4 rb0 = *(const uint4*)(wb + (size_t)br0 * 256 + bc0);
    uint4 rb1 = *(const uint4*)(wb + (size_t)br1 * 256 + bc0);
    uint4 rb2 = *(const uint4*)(wb + (size_t)br2 * 256 + bc0);
    uint4 rb3 = *(const uint4*)(wb + (size_t)br3 * 256 + bc0);

    for (int k0 = 0; k0 < 256; k0 += 64) {
        __syncthreads();
        *(uint4*)&As[ar0 * LSQ + ac0] = ra0;
        *(uint4*)&As[ar1 * LSQ + ac0] = ra1;
        *(uint4*)&Bs[br0 * LSQ + bc0] = rb0;
        *(uint4*)&Bs[br1 * LSQ + bc0] = rb1;
        *(uint4*)&Bs[br2 * LSQ + bc0] = rb2;
        *(uint4*)&Bs[br3 * LSQ + bc0] = rb3;
        __syncthreads();

        const int kn = (k0 + 64) & 255;
        ra0 = *(const uint4*)(xb + (size_t)ar0 * 256 + kn + ac0);
        ra1 = *(const uint4*)(xb + (size_t)ar1 * 256 + kn + ac0);
        rb0 = *(const uint4*)(wb + (size_t)br0 * 256 + kn + bc0);
        rb1 = *(const uint4*)(wb + (size_t)br1 * 256 + kn + bc0);
        rb2 = *(const uint4*)(wb + (size_t)br2 * 256 + kn + bc0);
        rb3 = *(const uint4*)(wb + (size_t)br3 * 256 + kn + bc0);

#pragma unroll
        for (int kh = 0; kh < 2; ++kh) {
            bf16x8 af[2], bfg[4];
#pragma unroll
            for (int mi = 0; mi < 2; ++mi)
                af[mi]  = *(const bf16x8*)&As[(wm * 32 + mi * 16 + lq) * LSQ + kh * 32 + quad * 8];
#pragma unroll
            for (int ni = 0; ni < 4; ++ni)
                bfg[ni] = *(const bf16x8*)&Bs[(wn * 64 + ni * 16 + lq) * LSQ + kh * 32 + quad * 8];
            if (isV) {
#pragma unroll
                for (int mi = 0; mi < 2; ++mi)
#pragma unroll
                    for (int ni = 0; ni < 4; ++ni)
                        acc[mi * 4 + ni] = __builtin_amdgcn_mfma_f32_16x16x32_bf16(
                            af[mi], bfg[ni], acc[mi * 4 + ni], 0, 0, 0);
            } else {
#pragma unroll
                for (int ni = 0; ni < 4; ++ni)
#pragma unroll
                    for (int mi = 0; mi < 2; ++mi)
                        acc[ni * 2 + mi] = __builtin_amdgcn_mfma_f32_16x16x32_bf16(
                            bfg[ni], af[mi], acc[ni * 2 + mi], 0, 0, 0);
            }
        }
    }

    if (!isV) {
#pragma unroll
        for (int ni = 0; ni < 4; ++ni) {
            int nb = n0 + wn * 64 + ni * 16 + quad * 4;
            float4 bs = *(const float4*)(bias + nb);
            int h   = (nb >> 5) & 7;
            int dh0 = nb & 31;
            bool  isQ = (nb < 256);
            float sc  = isQ ? QSCALE : 1.0f;
            ushort* dst = isQ ? qo : ko;
#pragma unroll
            for (int mi = 0; mi < 2; ++mi) {
                int m   = m0 + wm * 32 + mi * 16 + lq;
                int b   = m >> 11, seq = m & 2047;
                f32x4 c = acc[ni * 2 + mi];
                ushort4 pk;
                pk.x = f2bf((c[0] + bs.x) * sc); pk.y = f2bf((c[1] + bs.y) * sc);
                pk.z = f2bf((c[2] + bs.z) * sc); pk.w = f2bf((c[3] + bs.w) * sc);
                *(ushort4*)&dst[(((size_t)b * NH + h) * SEQ + seq) * DH + dh0] = pk;
            }
        }
    } else {
#pragma unroll
        for (int ni = 0; ni < 4; ++ni) {
            int n  = n0 + wn * 64 + ni * 16 + lq;
            int h  = (n >> 5) & 7;
            int dh = n & 31;
            float bsc = bias[n];
#pragma unroll
            for (int mi = 0; mi < 2; ++mi) {
                int mb  = m0 + wm * 32 + mi * 16 + quad * 4;
                int b   = mb >> 11, seq = mb & 2047;
                f32x4 c = acc[mi * 4 + ni];
                ushort4 pk;
                pk.x = f2bf(c[0] + bsc); pk.y = f2bf(c[1] + bsc);
                pk.z = f2bf(c[2] + bsc); pk.w = f2bf(c[3] + bsc);
                *(ushort4*)&vo[(((size_t)b * NH + h) * DH + dh) * SEQ + seq] = pk;
            }
        }
    }
}

// ---------------------------------------------------------------------------
// Kernel 2: MFMA flash attention v4 — kt-split (2 halves) + two-pass P
// (LDS 37.4 KB, 4 blocks/CU) + fused per-tile S->exp->pack. (r12)
// ---------------------------------------------------------------------------
__global__ __launch_bounds__(256, 4) void attn_mfma(
    const ushort* __restrict__ qb, const ushort* __restrict__ kb,
    const ushort* __restrict__ vtb,
    float* __restrict__ Opart, float* __restrict__ Lpart)
{
    __shared__ ushort Ks[128 * KS_STRIDE];
    __shared__ ushort VsT[32 * VT_STRIDE];
    __shared__ ushort Pl[4 * 32 * P2_STRIDE];

    const int tid  = threadIdx.x;
    const int wid  = tid >> 6;
    const int lane = tid & 63;
    const int lq   = lane & 15;
    const int quad = lane >> 4;
    const int qt   = blockIdx.x & 15;
    const int half = blockIdx.x >> 4;
    const int h    = blockIdx.y;
    const int b    = blockIdx.z;
    const int bh   = b * NH + h;
    const int q0   = qt * 128 + wid * 32;
    const int kt0  = half * 1024;

    const ushort* qbase = qb + ((size_t)bh * SEQ + q0) * DH;
    const bf16x8 qf0 = *(const bf16x8*)(qbase + (size_t)lq * DH + quad * 8);
    const bf16x8 qf1 = *(const bf16x8*)(qbase + (size_t)(16 + lq) * DH + quad * 8);

    const ushort* kbase  = kb  + (size_t)bh * SEQ * DH + (size_t)kt0 * DH;
    const ushort* vtbase = vtb + (size_t)bh * DH * SEQ + kt0;
    ushort* Pw = Pl + wid * 32 * P2_STRIDE;

    const int f0 = tid, f1 = tid + 256;
    const int kgo0 = (f0 >> 2) * DH + (f0 & 3) * 8;
    const int kgo1 = (f1 >> 2) * DH + (f1 & 3) * 8;
    const int klo0 = (f0 >> 2) * KS_STRIDE + (f0 & 3) * 8;
    const int klo1 = (f1 >> 2) * KS_STRIDE + (f1 & 3) * 8;
    const int vgo0 = (f0 >> 4) * SEQ + (f0 & 15) * 8;
    const int vgo1 = (f1 >> 4) * SEQ + (f1 & 15) * 8;
    const int vlo0 = (f0 >> 4) * VT_STRIDE + (f0 & 15) * 8;
    const int vlo1 = (f1 >> 4) * VT_STRIDE + (f1 & 15) * 8;

    uint4 kr0 = *(const uint4*)(kbase  + kgo0);
    uint4 kr1 = *(const uint4*)(kbase  + kgo1);
    uint4 vr0 = *(const uint4*)(vtbase + vgo0);
    uint4 vr1 = *(const uint4*)(vtbase + vgo1);

    f32x4 o0 = {0.f,0.f,0.f,0.f}, o1 = {0.f,0.f,0.f,0.f};
    f32x4 o2 = {0.f,0.f,0.f,0.f}, o3 = {0.f,0.f,0.f,0.f};
    f32x4 la0 = {0.f,0.f,0.f,0.f}, la1 = {0.f,0.f,0.f,0.f};
    const bf16x8 ones = {0x3F80, 0x3F80, 0x3F80, 0x3F80,
                         0x3F80, 0x3F80, 0x3F80, 0x3F80};

    for (int it = 0; it < 8; ++it) {
        __syncthreads();
        *(uint4*)&Ks[klo0]  = kr0;
        *(uint4*)&Ks[klo1]  = kr1;
        *(uint4*)&VsT[vlo0] = vr0;
        *(uint4*)&VsT[vlo1] = vr1;
        __syncthreads();

        {   // unconditional prefetch, wraps within the half (unused last iter)
            const int koff = ((it + 1) & 7) * 128;
            const ushort* kn = kbase  + (size_t)koff * DH;
            const ushort* vn = vtbase + koff;
            kr0 = *(const uint4*)(kn + kgo0);
            kr1 = *(const uint4*)(kn + kgo1);
            vr0 = *(const uint4*)(vn + vgo0);
            vr1 = *(const uint4*)(vn + vgo1);
        }

#pragma unroll
        for (int pass = 0; pass < 2; ++pass) {
#pragma unroll
            for (int tt = 0; tt < 4; ++tt) {
                const int t = pass * 4 + tt;
                bf16x8 kf = *(const bf16x8*)&Ks[(t * 16 + lq) * KS_STRIDE + quad * 8];
                f32x4 z = {0.f, 0.f, 0.f, 0.f};
                f32x4 s0 = __builtin_amdgcn_mfma_f32_16x16x32_bf16(kf, qf0, z, 0, 0, 0);
                f32x4 s1 = __builtin_amdgcn_mfma_f32_16x16x32_bf16(kf, qf1, z, 0, 0, 0);
                uint2 w2;
                w2.x = pk2(__builtin_amdgcn_exp2f(s0[0]), __builtin_amdgcn_exp2f(s0[1]));
                w2.y = pk2(__builtin_amdgcn_exp2f(s0[2]), __builtin_amdgcn_exp2f(s0[3]));
                *(uint2*)&Pw[lq * P2_STRIDE + tt * 16 + quad * 4] = w2;
                w2.x = pk2(__builtin_amdgcn_exp2f(s1[0]), __builtin_amdgcn_exp2f(s1[1]));
                w2.y = pk2(__builtin_amdgcn_exp2f(s1[2]), __builtin_amdgcn_exp2f(s1[3]));
                *(uint2*)&Pw[(16 + lq) * P2_STRIDE + tt * 16 + quad * 4] = w2;
            }
#pragma unroll
            for (int sc = 0; sc < 2; ++sc) {
                const int vcol = pass * 64 + sc * 32;
                bf16x8 v0 = *(const bf16x8*)&VsT[lq        * VT_STRIDE + vcol + quad * 8];
                bf16x8 v1 = *(const bf16x8*)&VsT[(16 + lq) * VT_STRIDE + vcol + quad * 8];
                bf16x8 p0 = *(const bf16x8*)&Pw[lq        * P2_STRIDE + sc * 32 + quad * 8];
                bf16x8 p1 = *(const bf16x8*)&Pw[(16 + lq) * P2_STRIDE + sc * 32 + quad * 8];
                o0  = __builtin_amdgcn_mfma_f32_16x16x32_bf16(v0,   p0, o0,  0, 0, 0);
                o1  = __builtin_amdgcn_mfma_f32_16x16x32_bf16(v1,   p0, o1,  0, 0, 0);
                o2  = __builtin_amdgcn_mfma_f32_16x16x32_bf16(v0,   p1, o2,  0, 0, 0);
                o3  = __builtin_amdgcn_mfma_f32_16x16x32_bf16(v1,   p1, o3,  0, 0, 0);
                la0 = __builtin_amdgcn_mfma_f32_16x16x32_bf16(ones, p0, la0, 0, 0, 0);
                la1 = __builtin_amdgcn_mfma_f32_16x16x32_bf16(ones, p1, la1, 0, 0, 0);
            }
        }
    }

    float* od0 = Opart + (size_t)half * MTOT * DMODEL
               + ((size_t)b * SEQ + q0 + lq) * DMODEL + h * DH;
    float* od1 = od0 + 16 * DMODEL;
    *(float4*)&od0[quad * 4]      = make_float4(o0[0], o0[1], o0[2], o0[3]);
    *(float4*)&od0[16 + quad * 4] = make_float4(o1[0], o1[1], o1[2], o1[3]);
    *(float4*)&od1[quad * 4]      = make_float4(o2[0], o2[1], o2[2], o2[3]);
    *(float4*)&od1[16 + quad * 4] = make_float4(o3[0], o3[1], o3[2], o3[3]);
    if (quad == 0) {
        float* ld = Lpart + (size_t)half * (BATCH * NH * SEQ) + (size_t)bh * SEQ;
        ld[q0 + lq]      = la0[0];
        ld[q0 + 16 + lq] = la1[0];
    }
}

// ---------------------------------------------------------------------------
// Kernel 3: out projection with FUSED combine.  A-staging reads both fp32
// O-partials (L2-hot) + partial l's and produces the normalized bf16 A tile
// on the fly — the separate combine kernel and a_bf buffer are gone.
// Tile 64x64, BK=64, grid (4,128) = 512 blocks.
// ---------------------------------------------------------------------------
__global__ __launch_bounds__(256) void out_gemm_fused(
    const float* __restrict__ Opart, const float* __restrict__ Lpart,
    const ushort* __restrict__ wT, const float* __restrict__ bias,
    float* __restrict__ out)
{
    __shared__ ushort As[64 * LSQ];
    __shared__ ushort Bs[64 * LSQ];
    const int tid  = threadIdx.x;
    const int wid  = tid >> 6;
    const int lane = tid & 63;
    const int lq   = lane & 15;
    const int quad = lane >> 4;
    const int wm   = wid & 1;
    const int wn   = wid >> 1;
    const int m0   = blockIdx.y * 64;
    const int n0   = blockIdx.x * 64;

    const int r0 = tid >> 3, c0 = (tid & 7) * 8;
    const int r1 = r0 + 32;                      // (tid+256)>>3, same c0

    const size_t HOFF = (size_t)MTOT * DMODEL;   // second O half
    const int    LOFF = BATCH * NH * SEQ;        // second l half
    const int gm0 = m0 + r0, gm1 = m0 + r1;
    const int b0i = gm0 >> 11, s0i = gm0 & 2047;
    const int b1i = gm1 >> 11, s1i = gm1 & 2047;

    const ushort* wb = wT + (size_t)n0 * 256;

    f32x4 acc[4];
#pragma unroll
    for (int i = 0; i < 4; ++i) acc[i] = {0.f, 0.f, 0.f, 0.f};

    // ---- prefetch (k-offset kk): O chunks + l's, all unconditional ----
    float4 A00, A01, B00, B01, A10, A11, B10, B11;
    float  L0a, L0b, L1a, L1b;
    uint4  rb0, rb1;
    {
        const int kk = 0;
        const int gc = kk + c0, hh = gc >> 5;
        const size_t i0 = (size_t)gm0 * 256 + gc;
        const size_t i1 = (size_t)gm1 * 256 + gc;
        const size_t l0 = ((size_t)(b0i * NH + hh)) * SEQ + s0i;
        const size_t l1 = ((size_t)(b1i * NH + hh)) * SEQ + s1i;
        A00 = *(const float4*)(Opart + i0);        A01 = *(const float4*)(Opart + i0 + 4);
        B00 = *(const float4*)(Opart + HOFF + i0); B01 = *(const float4*)(Opart + HOFF + i0 + 4);
        A10 = *(const float4*)(Opart + i1);        A11 = *(const float4*)(Opart + i1 + 4);
        B10 = *(const float4*)(Opart + HOFF + i1); B11 = *(const float4*)(Opart + HOFF + i1 + 4);
        L0a = Lpart[l0]; L0b = Lpart[LOFF + l0];
        L1a = Lpart[l1]; L1b = Lpart[LOFF + l1];
        rb0 = *(const uint4*)(wb + (size_t)r0 * 256 + c0);
        rb1 = *(const uint4*)(wb + (size_t)r1 * 256 + c0);
    }

    for (int k0 = 0; k0 < 256; k0 += 64) {
        __syncthreads();
        {   // stage A: combine-on-the-fly -> bf16
            float inv0 = 1.0f / (L0a + L0b);
            float inv1 = 1.0f / (L1a + L1b);
            uint4 u;
            u.x = pk2((A00.x + B00.x) * inv0, (A00.y + B00.y) * inv0);
            u.y = pk2((A00.z + B00.z) * inv0, (A00.w + B00.w) * inv0);
            u.z = pk2((A01.x + B01.x) * inv0, (A01.y + B01.y) * inv0);
            u.w = pk2((A01.z + B01.z) * inv0, (A01.w + B01.w) * inv0);
            *(uint4*)&As[r0 * LSQ + c0] = u;
            u.x = pk2((A10.x + B10.x) * inv1, (A10.y + B10.y) * inv1);
            u.y = pk2((A10.z + B10.z) * inv1, (A10.w + B10.w) * inv1);
            u.z = pk2((A11.x + B11.x) * inv1, (A11.y + B11.y) * inv1);
            u.w = pk2((A11.z + B11.z) * inv1, (A11.w + B11.w) * inv1);
            *(uint4*)&As[r1 * LSQ + c0] = u;
        }
        *(uint4*)&Bs[r0 * LSQ + c0] = rb0;
        *(uint4*)&Bs[r1 * LSQ + c0] = rb1;
        __syncthreads();

        {   // unconditional prefetch of next k-strip (wraps on last iter)
            const int kk = (k0 + 64) & 255;
            const int gc = kk + c0, hh = gc >> 5;
            const size_t i0 = (size_t)gm0 * 256 + gc;
            const size_t i1 = (size_t)gm1 * 256 + gc;
            const size_t l0 = ((size_t)(b0i * NH + hh)) * SEQ + s0i;
            const size_t l1 = ((size_t)(b1i * NH + hh)) * SEQ + s1i;
            A00 = *(const float4*)(Opart + i0);        A01 = *(const float4*)(Opart + i0 + 4);
            B00 = *(const float4*)(Opart + HOFF + i0); B01 = *(const float4*)(Opart + HOFF + i0 + 4);
            A10 = *(const float4*)(Opart + i1);        A11 = *(const float4*)(Opart + i1 + 4);
            B10 = *(const float4*)(Opart + HOFF + i1); B11 = *(const float4*)(Opart + HOFF + i1 + 4);
            L0a = Lpart[l0]; L0b = Lpart[LOFF + l0];
            L1a = Lpart[l1]; L1b = Lpart[LOFF + l1];
            rb0 = *(const uint4*)(wb + (size_t)r0 * 256 + kk + c0);
            rb1 = *(const uint4*)(wb + (size_t)r1 * 256 + kk + c0);
        }

#pragma unroll
        for (int kh = 0; kh < 2; ++kh) {
            bf16x8 af[2], bfg[2];
#pragma unroll
            for (int mi = 0; mi < 2; ++mi)
                af[mi]  = *(const bf16x8*)&As[(wm * 32 + mi * 16 + lq) * LSQ + kh * 32 + quad * 8];
#pragma unroll
            for (int ni = 0; ni < 2; ++ni)
                bfg[ni] = *(const bf16x8*)&Bs[(wn * 32 + ni * 16 + lq) * LSQ + kh * 32 + quad * 8];
#pragma unroll
            for (int ni = 0; ni < 2; ++ni)
#pragma unroll
                for (int mi = 0; mi < 2; ++mi)
                    acc[ni * 2 + mi] = __builtin_amdgcn_mfma_f32_16x16x32_bf16(
                        bfg[ni], af[mi], acc[ni * 2 + mi], 0, 0, 0);
        }
    }

#pragma unroll
    for (int ni = 0; ni < 2; ++ni) {
        int nb = n0 + wn * 32 + ni * 16 + quad * 4;
        float4 bs = *(const float4*)(bias + nb);
#pragma unroll
        for (int mi = 0; mi < 2; ++mi) {
            int m = m0 + wm * 32 + mi * 16 + lq;
            f32x4 c = acc[ni * 2 + mi];
            float4 o;
            o.x = c[0] + bs.x; o.y = c[1] + bs.y;
            o.z = c[2] + bs.z; o.w = c[3] + bs.w;
            *(float4*)&out[(size_t)m * DMODEL + nb] = o;
        }
    }
}

extern "C" void kernel_launch(void* const* d_in, const int* in_sizes, int n_in,
                              void* d_out, int out_size, void* d_ws, size_t ws_size,
                              hipStream_t stream) {
    const float* x     = (const float*)d_in[0];
    const float* w_qkv = (const float*)d_in[1];
    const float* b_qkv = (const float*)d_in[2];
    const float* w_out = (const float*)d_in[3];
    const float* b_out = (const float*)d_in[4];
    float* out = (float*)d_out;

    const size_t TSZ = (size_t)MTOT * DMODEL;        // 2,097,152 elems
    ushort* q_ws = (ushort*)d_ws;                    // bf16 [b,h,s,dh], pre-scaled
    ushort* k_ws = q_ws + TSZ;                       // bf16 [b,h,s,dh]
    ushort* v_ws = k_ws + TSZ;                       // bf16 V^T [b,h,dh,s]
    ushort* xbf  = v_ws + TSZ;                       // bf16 x
    ushort* wqT  = xbf + TSZ;
    ushort* woT  = wqT + 768 * 256;
    float*  Opart = (float*)(woT + 256 * 256);       // 2 x TSZ fp32 (16 MB)
    float*  Lpart = Opart + 2 * TSZ;                 // 2 x 65536 fp32

    wcvt_all<<<dim3(96, 8), 256, 0, stream>>>(w_qkv, w_out, x, wqT, woT, xbf);
    qkv_gemm<<<dim3(6, 128), 256, 0, stream>>>(xbf, wqT, b_qkv, q_ws, k_ws, v_ws);
    attn_mfma<<<dim3(32, NH, BATCH), 256, 0, stream>>>(
        q_ws, k_ws, v_ws, Opart, Lpart);
    out_gemm_fused<<<dim3(4, 128), 256, 0, stream>>>(
        Opart, Lpart, woT, b_out, out);
}

// Round 14
// 123.960 us; speedup vs baseline: 1.0090x; 1.0090x over previous
//
#include <hip/hip_runtime.h>
#include <hip/hip_bf16.h>
#include <math.h>

#define BATCH  4
#define SEQ    2048
#define DMODEL 256
#define NH     8
#define DH     32
#define MTOT   (BATCH*SEQ)   // 8192
// Q is pre-scaled by 256^-0.5 * log2(e) so attention uses p = exp2(q.k) raw.
#define QSCALE 0.09016844005556021f

typedef short  bf16x8 __attribute__((ext_vector_type(8)));
typedef float  f32x4  __attribute__((ext_vector_type(4)));

static __device__ __forceinline__ ushort f2bf(float f) {
    __hip_bfloat16 h = __float2bfloat16(f);
    return __builtin_bit_cast(ushort, h);
}
static __device__ __forceinline__ uint rne2(float a, float b) {
    uint ua = __builtin_bit_cast(uint, a);
    uint ub = __builtin_bit_cast(uint, b);
    ua += 0x7FFFu + ((ua >> 16) & 1u);
    ub += 0x7FFFu + ((ub >> 16) & 1u);
    return __builtin_amdgcn_perm(ub, ua, 0x07060302);
}
static __device__ __forceinline__ uint pk2(float a, float b) {
#if __has_builtin(__builtin_amdgcn_cvt_pk_bf16_f32)
    auto r = __builtin_amdgcn_cvt_pk_bf16_f32(a, b);
    return __builtin_bit_cast(uint, r);
#else
    return rne2(a, b);
#endif
}

#define LSQ 72       // qkv/out LDS row stride (64 + 8 pad), ushorts
#define KS_STRIDE 40
#define VT_STRIDE 136
#define P2_STRIDE 72   // two-pass P: 64 cols + 8 pad

// ---------------------------------------------------------------------------
// Kernel 0: weight transposes + x fp32->bf16 conversion. (r11, proven)
// ---------------------------------------------------------------------------
__global__ __launch_bounds__(256) void wcvt_all(
    const float* __restrict__ wq, const float* __restrict__ wo,
    const float* __restrict__ x,
    ushort* __restrict__ wqT, ushort* __restrict__ woT,
    ushort* __restrict__ xbf)
{
    const int t  = threadIdx.x;
    const int bx = blockIdx.x;
    if (bx >= 32) {
        const size_t base = ((size_t)(bx - 32) * 8 + blockIdx.y) * 4096 + t * 16;
        float4 f0 = *(const float4*)(x + base);
        float4 f1 = *(const float4*)(x + base + 4);
        float4 f2 = *(const float4*)(x + base + 8);
        float4 f3 = *(const float4*)(x + base + 12);
        uint4 w0, w1;
        w0.x = pk2(f0.x, f0.y); w0.y = pk2(f0.z, f0.w);
        w0.z = pk2(f1.x, f1.y); w0.w = pk2(f1.z, f1.w);
        w1.x = pk2(f2.x, f2.y); w1.y = pk2(f2.z, f2.w);
        w1.z = pk2(f3.x, f3.y); w1.w = pk2(f3.z, f3.w);
        *(uint4*)&xbf[base]     = w0;
        *(uint4*)&xbf[base + 8] = w1;
        return;
    }
    __shared__ float T[32][33];
    const float* w; ushort* wT; int N, n0;
    if (bx < 24) { w = wq; wT = wqT; N = 768; n0 = bx * 32; }
    else         { w = wo; wT = woT; N = 256; n0 = (bx - 24) * 32; }
    const int k0 = blockIdx.y * 32;
    {
        int tr = t >> 3, tc = (t & 7) * 4;
        *(float4*)&T[tr][tc] = *(const float4*)(w + (size_t)(k0 + tr) * N + n0 + tc);
    }
    __syncthreads();
    int nl = t >> 3, kq = (t & 7) * 4;
    ushort4 pk;
    pk.x = f2bf(T[kq + 0][nl]); pk.y = f2bf(T[kq + 1][nl]);
    pk.z = f2bf(T[kq + 2][nl]); pk.w = f2bf(T[kq + 3][nl]);
    *(ushort4*)&wT[(size_t)(n0 + nl) * 256 + k0 + kq] = pk;
}

// ---------------------------------------------------------------------------
// Kernel 1: QKV projection, bf16 MFMA, scalar reg-prefetch. (r8/r11, proven)
// ---------------------------------------------------------------------------
__global__ __launch_bounds__(256, 3) void qkv_gemm(
    const ushort* __restrict__ xb_, const ushort* __restrict__ wT,
    const float* __restrict__ bias,
    ushort* __restrict__ qo, ushort* __restrict__ ko, ushort* __restrict__ vo)
{
    __shared__ ushort As[64 * LSQ];
    __shared__ ushort Bs[128 * LSQ];
    const int tid  = threadIdx.x;
    const int wid  = tid >> 6;
    const int lane = tid & 63;
    const int lq   = lane & 15;
    const int quad = lane >> 4;
    const int wm   = wid & 1;
    const int wn   = wid >> 1;
    const int m0   = blockIdx.y * 64;
    const int n0   = blockIdx.x * 128;
    const bool isV = (blockIdx.x >= 4);

    const int ar0 = tid >> 3,         ac0 = (tid & 7) * 8;
    const int ar1 = (tid + 256) >> 3;
    const int br0 = tid >> 3,         bc0 = (tid & 7) * 8;
    const int br1 = (tid + 256) >> 3;
    const int br2 = (tid + 512) >> 3;
    const int br3 = (tid + 768) >> 3;

    const ushort* xb = xb_ + (size_t)m0 * 256;
    const ushort* wb = wT  + (size_t)n0 * 256;

    f32x4 acc[8];
#pragma unroll
    for (int i = 0; i < 8; ++i) acc[i] = {0.f, 0.f, 0.f, 0.f};

    uint4 ra0 = *(const uint4*)(xb + (size_t)ar0 * 256 + ac0);
    uint4 ra1 = *(const uint4*)(xb + (size_t)ar1 * 256 + ac0);
    uint4 rb0 = *(const uint4*)(wb + (size_t)br0 * 256 + bc0);
    uint4 rb1 = *(const uint4*)(wb + (size_t)br1 * 256 + bc0);
    uint4 rb2 = *(const uint4*)(wb + (size_t)br2 * 256 + bc0);
    uint4 rb3 = *(const uint4*)(wb + (size_t)br3 * 256 + bc0);

    for (int k0 = 0; k0 < 256; k0 += 64) {
        __syncthreads();
        *(uint4*)&As[ar0 * LSQ + ac0] = ra0;
        *(uint4*)&As[ar1 * LSQ + ac0] = ra1;
        *(uint4*)&Bs[br0 * LSQ + bc0] = rb0;
        *(uint4*)&Bs[br1 * LSQ + bc0] = rb1;
        *(uint4*)&Bs[br2 * LSQ + bc0] = rb2;
        *(uint4*)&Bs[br3 * LSQ + bc0] = rb3;
        __syncthreads();

        const int kn = (k0 + 64) & 255;
        ra0 = *(const uint4*)(xb + (size_t)ar0 * 256 + kn + ac0);
        ra1 = *(const uint4*)(xb + (size_t)ar1 * 256 + kn + ac0);
        rb0 = *(const uint4*)(wb + (size_t)br0 * 256 + kn + bc0);
        rb1 = *(const uint4*)(wb + (size_t)br1 * 256 + kn + bc0);
        rb2 = *(const uint4*)(wb + (size_t)br2 * 256 + kn + bc0);
        rb3 = *(const uint4*)(wb + (size_t)br3 * 256 + kn + bc0);

#pragma unroll
        for (int kh = 0; kh < 2; ++kh) {
            bf16x8 af[2], bfg[4];
#pragma unroll
            for (int mi = 0; mi < 2; ++mi)
                af[mi]  = *(const bf16x8*)&As[(wm * 32 + mi * 16 + lq) * LSQ + kh * 32 + quad * 8];
#pragma unroll
            for (int ni = 0; ni < 4; ++ni)
                bfg[ni] = *(const bf16x8*)&Bs[(wn * 64 + ni * 16 + lq) * LSQ + kh * 32 + quad * 8];
            if (isV) {
#pragma unroll
                for (int mi = 0; mi < 2; ++mi)
#pragma unroll
                    for (int ni = 0; ni < 4; ++ni)
                        acc[mi * 4 + ni] = __builtin_amdgcn_mfma_f32_16x16x32_bf16(
                            af[mi], bfg[ni], acc[mi * 4 + ni], 0, 0, 0);
            } else {
#pragma unroll
                for (int ni = 0; ni < 4; ++ni)
#pragma unroll
                    for (int mi = 0; mi < 2; ++mi)
                        acc[ni * 2 + mi] = __builtin_amdgcn_mfma_f32_16x16x32_bf16(
                            bfg[ni], af[mi], acc[ni * 2 + mi], 0, 0, 0);
            }
        }
    }

    if (!isV) {
#pragma unroll
        for (int ni = 0; ni < 4; ++ni) {
            int nb = n0 + wn * 64 + ni * 16 + quad * 4;
            float4 bs = *(const float4*)(bias + nb);
            int h   = (nb >> 5) & 7;
            int dh0 = nb & 31;
            bool  isQ = (nb < 256);
            float sc  = isQ ? QSCALE : 1.0f;
            ushort* dst = isQ ? qo : ko;
#pragma unroll
            for (int mi = 0; mi < 2; ++mi) {
                int m   = m0 + wm * 32 + mi * 16 + lq;
                int b   = m >> 11, seq = m & 2047;
                f32x4 c = acc[ni * 2 + mi];
                ushort4 pk;
                pk.x = f2bf((c[0] + bs.x) * sc); pk.y = f2bf((c[1] + bs.y) * sc);
                pk.z = f2bf((c[2] + bs.z) * sc); pk.w = f2bf((c[3] + bs.w) * sc);
                *(ushort4*)&dst[(((size_t)b * NH + h) * SEQ + seq) * DH + dh0] = pk;
            }
        }
    } else {
#pragma unroll
        for (int ni = 0; ni < 4; ++ni) {
            int n  = n0 + wn * 64 + ni * 16 + lq;
            int h  = (n >> 5) & 7;
            int dh = n & 31;
            float bsc = bias[n];
#pragma unroll
            for (int mi = 0; mi < 2; ++mi) {
                int mb  = m0 + wm * 32 + mi * 16 + quad * 4;
                int b   = mb >> 11, seq = mb & 2047;
                f32x4 c = acc[mi * 4 + ni];
                ushort4 pk;
                pk.x = f2bf(c[0] + bsc); pk.y = f2bf(c[1] + bsc);
                pk.z = f2bf(c[2] + bsc); pk.w = f2bf(c[3] + bsc);
                *(ushort4*)&vo[(((size_t)b * NH + h) * DH + dh) * SEQ + seq] = pk;
            }
        }
    }
}

// ---------------------------------------------------------------------------
// Kernel 2: MFMA flash attention v5 — q-SPLIT for occupancy.
// 64 q/block (16 q/wave, one q-set), grid (32,8,4) = 1024 blocks = 4/CU.
// Two-pass P buffer (LDS total 28.2 KB).  Full kt range per block (no
// partial-O traffic — the r12/r13 mistake).  bf16 a_bf output, ones-MFMA l,
// HW pk2, unconditional scalar reg-prefetch — all r11-proven pieces.
// ---------------------------------------------------------------------------
__global__ __launch_bounds__(256, 4) void attn_mfma(
    const ushort* __restrict__ qb, const ushort* __restrict__ kb,
    const ushort* __restrict__ vtb, ushort* __restrict__ a_bf)
{
    __shared__ ushort Ks[128 * KS_STRIDE];      // 10240 B
    __shared__ ushort VsT[32 * VT_STRIDE];      //  8704 B
    __shared__ ushort Pl[4 * 16 * P2_STRIDE];   //  9216 B => 28160 B total

    const int tid  = threadIdx.x;
    const int wid  = tid >> 6;
    const int lane = tid & 63;
    const int lq   = lane & 15;
    const int quad = lane >> 4;
    const int h    = blockIdx.y;
    const int b    = blockIdx.z;
    const int bh   = b * NH + h;
    const int q0   = blockIdx.x * 64 + wid * 16;

    const bf16x8 qf = *(const bf16x8*)(qb + ((size_t)bh * SEQ + q0 + lq) * DH + quad * 8);

    const ushort* kbase  = kb  + (size_t)bh * SEQ * DH;
    const ushort* vtbase = vtb + (size_t)bh * DH * SEQ;
    ushort* Pw = Pl + wid * 16 * P2_STRIDE;

    const int f0 = tid, f1 = tid + 256;
    const int kgo0 = (f0 >> 2) * DH + (f0 & 3) * 8;
    const int kgo1 = (f1 >> 2) * DH + (f1 & 3) * 8;
    const int klo0 = (f0 >> 2) * KS_STRIDE + (f0 & 3) * 8;
    const int klo1 = (f1 >> 2) * KS_STRIDE + (f1 & 3) * 8;
    const int vgo0 = (f0 >> 4) * SEQ + (f0 & 15) * 8;
    const int vgo1 = (f1 >> 4) * SEQ + (f1 & 15) * 8;
    const int vlo0 = (f0 >> 4) * VT_STRIDE + (f0 & 15) * 8;
    const int vlo1 = (f1 >> 4) * VT_STRIDE + (f1 & 15) * 8;

    uint4 kr0 = *(const uint4*)(kbase  + kgo0);
    uint4 kr1 = *(const uint4*)(kbase  + kgo1);
    uint4 vr0 = *(const uint4*)(vtbase + vgo0);
    uint4 vr1 = *(const uint4*)(vtbase + vgo1);

    f32x4 o0  = {0.f,0.f,0.f,0.f};   // dh 0..15 (rows quad*4+reg), col q=lq
    f32x4 o1  = {0.f,0.f,0.f,0.f};   // dh 16..31
    f32x4 la0 = {0.f,0.f,0.f,0.f};   // l accumulator (ones-MFMA)
    const bf16x8 ones = {0x3F80, 0x3F80, 0x3F80, 0x3F80,
                         0x3F80, 0x3F80, 0x3F80, 0x3F80};

    for (int kt = 0; kt < SEQ; kt += 128) {
        __syncthreads();
        *(uint4*)&Ks[klo0]  = kr0;
        *(uint4*)&Ks[klo1]  = kr1;
        *(uint4*)&VsT[vlo0] = vr0;
        *(uint4*)&VsT[vlo1] = vr1;
        __syncthreads();

        {   // unconditional prefetch (wraps to 0 on last iter; value unused)
            const int ktn = (kt + 128) & (SEQ - 1);
            const ushort* kn = kbase  + (size_t)ktn * DH;
            const ushort* vn = vtbase + ktn;
            kr0 = *(const uint4*)(kn + kgo0);
            kr1 = *(const uint4*)(kn + kgo1);
            vr0 = *(const uint4*)(vn + vgo0);
            vr1 = *(const uint4*)(vn + vgo1);
        }

#pragma unroll
        for (int pass = 0; pass < 2; ++pass) {
            // ---- 4 tiles: S -> exp -> pack into P[16 x 64] ----
#pragma unroll
            for (int tt = 0; tt < 4; ++tt) {
                const int t = pass * 4 + tt;
                bf16x8 kf = *(const bf16x8*)&Ks[(t * 16 + lq) * KS_STRIDE + quad * 8];
                f32x4 z = {0.f, 0.f, 0.f, 0.f};
                f32x4 s0 = __builtin_amdgcn_mfma_f32_16x16x32_bf16(kf, qf, z, 0, 0, 0);
                uint2 w2;
                w2.x = pk2(__builtin_amdgcn_exp2f(s0[0]), __builtin_amdgcn_exp2f(s0[1]));
                w2.y = pk2(__builtin_amdgcn_exp2f(s0[2]), __builtin_amdgcn_exp2f(s0[3]));
                *(uint2*)&Pw[lq * P2_STRIDE + tt * 16 + quad * 4] = w2;
            }
            // ---- PV for this 64-col half (+ l via ones-MFMA) ----
#pragma unroll
            for (int sc = 0; sc < 2; ++sc) {
                const int vcol = pass * 64 + sc * 32;
                bf16x8 v0 = *(const bf16x8*)&VsT[lq        * VT_STRIDE + vcol + quad * 8];
                bf16x8 v1 = *(const bf16x8*)&VsT[(16 + lq) * VT_STRIDE + vcol + quad * 8];
                bf16x8 p0 = *(const bf16x8*)&Pw[lq * P2_STRIDE + sc * 32 + quad * 8];
                o0  = __builtin_amdgcn_mfma_f32_16x16x32_bf16(v0,   p0, o0,  0, 0, 0);
                o1  = __builtin_amdgcn_mfma_f32_16x16x32_bf16(v1,   p0, o1,  0, 0, 0);
                la0 = __builtin_amdgcn_mfma_f32_16x16x32_bf16(ones, p0, la0, 0, 0, 0);
            }
        }
    }

    // ---- epilogue: l = la0[0] (rows identical per col q=lq), bf16 out ----
    float inv = 1.0f / la0[0];
    ushort* dst = a_bf + ((size_t)b * SEQ + q0 + lq) * DMODEL + h * DH;
    uint2 w0, w1;
    w0.x = pk2(o0[0] * inv, o0[1] * inv);
    w0.y = pk2(o0[2] * inv, o0[3] * inv);
    w1.x = pk2(o1[0] * inv, o1[1] * inv);
    w1.y = pk2(o1[2] * inv, o1[3] * inv);
    *(uint2*)&dst[quad * 4]      = w0;
    *(uint2*)&dst[16 + quad * 4] = w1;
}

// ---------------------------------------------------------------------------
// Kernel 3: out projection, bf16 MFMA, scalar reg-prefetch. (r8/r11, proven)
// ---------------------------------------------------------------------------
__global__ __launch_bounds__(256) void out_gemm(
    const ushort* __restrict__ a, const ushort* __restrict__ wT,
    const float* __restrict__ bias, float* __restrict__ out)
{
    __shared__ ushort As[64 * LSQ];
    __shared__ ushort Bs[64 * LSQ];
    const int tid  = threadIdx.x;
    const int wid  = tid >> 6;
    const int lane = tid & 63;
    const int lq   = lane & 15;
    const int quad = lane >> 4;
    const int wm   = wid & 1;
    const int wn   = wid >> 1;
    const int m0   = blockIdx.y * 64;
    const int n0   = blockIdx.x * 64;

    const int f0 = tid, f1 = tid + 256;
    const int r0 = f0 >> 3, c0 = (f0 & 7) * 8;
    const int r1 = f1 >> 3, c1 = (f1 & 7) * 8;

    const ushort* ab = a  + (size_t)m0 * 256;
    const ushort* wb = wT + (size_t)n0 * 256;

    f32x4 acc[4];
#pragma unroll
    for (int i = 0; i < 4; ++i) acc[i] = {0.f, 0.f, 0.f, 0.f};

    uint4 ra0 = *(const uint4*)(ab + (size_t)r0 * 256 + c0);
    uint4 ra1 = *(const uint4*)(ab + (size_t)r1 * 256 + c1);
    uint4 rb0 = *(const uint4*)(wb + (size_t)r0 * 256 + c0);
    uint4 rb1 = *(const uint4*)(wb + (size_t)r1 * 256 + c1);

    for (int k0 = 0; k0 < 256; k0 += 64) {
        __syncthreads();
        *(uint4*)&As[r0 * LSQ + c0] = ra0;
        *(uint4*)&As[r1 * LSQ + c1] = ra1;
        *(uint4*)&Bs[r0 * LSQ + c0] = rb0;
        *(uint4*)&Bs[r1 * LSQ + c1] = rb1;
        __syncthreads();

        const int kn = (k0 + 64) & 255;
        ra0 = *(const uint4*)(ab + (size_t)r0 * 256 + kn + c0);
        ra1 = *(const uint4*)(ab + (size_t)r1 * 256 + kn + c1);
        rb0 = *(const uint4*)(wb + (size_t)r0 * 256 + kn + c0);
        rb1 = *(const uint4*)(wb + (size_t)r1 * 256 + kn + c1);

#pragma unroll
        for (int kh = 0; kh < 2; ++kh) {
            bf16x8 af[2], bfg[2];
#pragma unroll
            for (int mi = 0; mi < 2; ++mi)
                af[mi]  = *(const bf16x8*)&As[(wm * 32 + mi * 16 + lq) * LSQ + kh * 32 + quad * 8];
#pragma unroll
            for (int ni = 0; ni < 2; ++ni)
                bfg[ni] = *(const bf16x8*)&Bs[(wn * 32 + ni * 16 + lq) * LSQ + kh * 32 + quad * 8];
#pragma unroll
            for (int ni = 0; ni < 2; ++ni)
#pragma unroll
                for (int mi = 0; mi < 2; ++mi)
                    acc[ni * 2 + mi] = __builtin_amdgcn_mfma_f32_16x16x32_bf16(
                        bfg[ni], af[mi], acc[ni * 2 + mi], 0, 0, 0);
        }
    }

#pragma unroll
    for (int ni = 0; ni < 2; ++ni) {
        int nb = n0 + wn * 32 + ni * 16 + quad * 4;
        float4 bs = *(const float4*)(bias + nb);
#pragma unroll
        for (int mi = 0; mi < 2; ++mi) {
            int m = m0 + wm * 32 + mi * 16 + lq;
            f32x4 c = acc[ni * 2 + mi];
            float4 o;
            o.x = c[0] + bs.x; o.y = c[1] + bs.y;
            o.z = c[2] + bs.z; o.w = c[3] + bs.w;
            *(float4*)&out[(size_t)m * DMODEL + nb] = o;
        }
    }
}

extern "C" void kernel_launch(void* const* d_in, const int* in_sizes, int n_in,
                              void* d_out, int out_size, void* d_ws, size_t ws_size,
                              hipStream_t stream) {
    const float* x     = (const float*)d_in[0];
    const float* w_qkv = (const float*)d_in[1];
    const float* b_qkv = (const float*)d_in[2];
    const float* w_out = (const float*)d_in[3];
    const float* b_out = (const float*)d_in[4];
    float* out = (float*)d_out;

    const size_t TSZ = (size_t)MTOT * DMODEL;
    ushort* q_ws = (ushort*)d_ws;          // bf16 [b,h,s,dh], pre-scaled
    ushort* k_ws = q_ws + TSZ;             // bf16 [b,h,s,dh]
    ushort* v_ws = k_ws + TSZ;             // bf16 V^T [b,h,dh,s]
    ushort* a_bf = v_ws + TSZ;             // bf16 attn out [b,s,d]
    ushort* xbf  = a_bf + TSZ;             // bf16 x
    ushort* wqT  = xbf + TSZ;
    ushort* woT  = wqT + 768 * 256;

    wcvt_all<<<dim3(96, 8), 256, 0, stream>>>(w_qkv, w_out, x, wqT, woT, xbf);
    qkv_gemm<<<dim3(6, 128), 256, 0, stream>>>(xbf, wqT, b_qkv, q_ws, k_ws, v_ws);
    attn_mfma<<<dim3(32, NH, BATCH), 256, 0, stream>>>(
        q_ws, k_ws, v_ws, a_bf);
    out_gemm<<<dim3(4, 128), 256, 0, stream>>>(a_bf, woT, b_out, out);
}

// Round 15
// 121.255 us; speedup vs baseline: 1.0315x; 1.0223x over previous
//
#include <hip/hip_runtime.h>
#include <hip/hip_bf16.h>
#include <math.h>

#define BATCH  4
#define SEQ    2048
#define DMODEL 256
#define NH     8
#define DH     32
#define MTOT   (BATCH*SEQ)   // 8192
// Q is pre-scaled by 256^-0.5 * log2(e) so attention uses p = exp2(q.k) raw.
#define QSCALE 0.09016844005556021f

typedef short  bf16x8 __attribute__((ext_vector_type(8)));
typedef float  f32x4  __attribute__((ext_vector_type(4)));

static __device__ __forceinline__ ushort f2bf(float f) {
    __hip_bfloat16 h = __float2bfloat16(f);
    return __builtin_bit_cast(ushort, h);
}
static __device__ __forceinline__ uint rne2(float a, float b) {
    uint ua = __builtin_bit_cast(uint, a);
    uint ub = __builtin_bit_cast(uint, b);
    ua += 0x7FFFu + ((ua >> 16) & 1u);
    ub += 0x7FFFu + ((ub >> 16) & 1u);
    return __builtin_amdgcn_perm(ub, ua, 0x07060302);
}
static __device__ __forceinline__ uint pk2(float a, float b) {
#if __has_builtin(__builtin_amdgcn_cvt_pk_bf16_f32)
    auto r = __builtin_amdgcn_cvt_pk_bf16_f32(a, b);
    return __builtin_bit_cast(uint, r);
#else
    return rne2(a, b);
#endif
}

#define LSQ 72       // qkv/out LDS row stride (64 + 8 pad), ushorts
#define KS_STRIDE 40
#define VT_STRIDE 136
#define P2_STRIDE 72   // two-pass P: 64 cols + 8 pad

// ---------------------------------------------------------------------------
// Kernel 0: weight transposes + x fp32->bf16 conversion. (r11, proven)
// ---------------------------------------------------------------------------
__global__ __launch_bounds__(256) void wcvt_all(
    const float* __restrict__ wq, const float* __restrict__ wo,
    const float* __restrict__ x,
    ushort* __restrict__ wqT, ushort* __restrict__ woT,
    ushort* __restrict__ xbf)
{
    const int t  = threadIdx.x;
    const int bx = blockIdx.x;
    if (bx >= 32) {
        const size_t base = ((size_t)(bx - 32) * 8 + blockIdx.y) * 4096 + t * 16;
        float4 f0 = *(const float4*)(x + base);
        float4 f1 = *(const float4*)(x + base + 4);
        float4 f2 = *(const float4*)(x + base + 8);
        float4 f3 = *(const float4*)(x + base + 12);
        uint4 w0, w1;
        w0.x = pk2(f0.x, f0.y); w0.y = pk2(f0.z, f0.w);
        w0.z = pk2(f1.x, f1.y); w0.w = pk2(f1.z, f1.w);
        w1.x = pk2(f2.x, f2.y); w1.y = pk2(f2.z, f2.w);
        w1.z = pk2(f3.x, f3.y); w1.w = pk2(f3.z, f3.w);
        *(uint4*)&xbf[base]     = w0;
        *(uint4*)&xbf[base + 8] = w1;
        return;
    }
    __shared__ float T[32][33];
    const float* w; ushort* wT; int N, n0;
    if (bx < 24) { w = wq; wT = wqT; N = 768; n0 = bx * 32; }
    else         { w = wo; wT = woT; N = 256; n0 = (bx - 24) * 32; }
    const int k0 = blockIdx.y * 32;
    {
        int tr = t >> 3, tc = (t & 7) * 4;
        *(float4*)&T[tr][tc] = *(const float4*)(w + (size_t)(k0 + tr) * N + n0 + tc);
    }
    __syncthreads();
    int nl = t >> 3, kq = (t & 7) * 4;
    ushort4 pk;
    pk.x = f2bf(T[kq + 0][nl]); pk.y = f2bf(T[kq + 1][nl]);
    pk.z = f2bf(T[kq + 2][nl]); pk.w = f2bf(T[kq + 3][nl]);
    *(ushort4*)&wT[(size_t)(n0 + nl) * 256 + k0 + kq] = pk;
}

// ---------------------------------------------------------------------------
// Kernel 1: QKV projection, bf16 MFMA, scalar reg-prefetch. (r8/r11, proven)
// ---------------------------------------------------------------------------
__global__ __launch_bounds__(256, 3) void qkv_gemm(
    const ushort* __restrict__ xb_, const ushort* __restrict__ wT,
    const float* __restrict__ bias,
    ushort* __restrict__ qo, ushort* __restrict__ ko, ushort* __restrict__ vo)
{
    __shared__ ushort As[64 * LSQ];
    __shared__ ushort Bs[128 * LSQ];
    const int tid  = threadIdx.x;
    const int wid  = tid >> 6;
    const int lane = tid & 63;
    const int lq   = lane & 15;
    const int quad = lane >> 4;
    const int wm   = wid & 1;
    const int wn   = wid >> 1;
    const int m0   = blockIdx.y * 64;
    const int n0   = blockIdx.x * 128;
    const bool isV = (blockIdx.x >= 4);

    const int ar0 = tid >> 3,         ac0 = (tid & 7) * 8;
    const int ar1 = (tid + 256) >> 3;
    const int br0 = tid >> 3,         bc0 = (tid & 7) * 8;
    const int br1 = (tid + 256) >> 3;
    const int br2 = (tid + 512) >> 3;
    const int br3 = (tid + 768) >> 3;

    const ushort* xb = xb_ + (size_t)m0 * 256;
    const ushort* wb = wT  + (size_t)n0 * 256;

    f32x4 acc[8];
#pragma unroll
    for (int i = 0; i < 8; ++i) acc[i] = {0.f, 0.f, 0.f, 0.f};

    uint4 ra0 = *(const uint4*)(xb + (size_t)ar0 * 256 + ac0);
    uint4 ra1 = *(const uint4*)(xb + (size_t)ar1 * 256 + ac0);
    uint4 rb0 = *(const uint4*)(wb + (size_t)br0 * 256 + bc0);
    uint4 rb1 = *(const uint4*)(wb + (size_t)br1 * 256 + bc0);
    uint4 rb2 = *(const uint4*)(wb + (size_t)br2 * 256 + bc0);
    uint4 rb3 = *(const uint4*)(wb + (size_t)br3 * 256 + bc0);

    for (int k0 = 0; k0 < 256; k0 += 64) {
        __syncthreads();
        *(uint4*)&As[ar0 * LSQ + ac0] = ra0;
        *(uint4*)&As[ar1 * LSQ + ac0] = ra1;
        *(uint4*)&Bs[br0 * LSQ + bc0] = rb0;
        *(uint4*)&Bs[br1 * LSQ + bc0] = rb1;
        *(uint4*)&Bs[br2 * LSQ + bc0] = rb2;
        *(uint4*)&Bs[br3 * LSQ + bc0] = rb3;
        __syncthreads();

        const int kn = (k0 + 64) & 255;
        ra0 = *(const uint4*)(xb + (size_t)ar0 * 256 + kn + ac0);
        ra1 = *(const uint4*)(xb + (size_t)ar1 * 256 + kn + ac0);
        rb0 = *(const uint4*)(wb + (size_t)br0 * 256 + kn + bc0);
        rb1 = *(const uint4*)(wb + (size_t)br1 * 256 + kn + bc0);
        rb2 = *(const uint4*)(wb + (size_t)br2 * 256 + kn + bc0);
        rb3 = *(const uint4*)(wb + (size_t)br3 * 256 + kn + bc0);

#pragma unroll
        for (int kh = 0; kh < 2; ++kh) {
            bf16x8 af[2], bfg[4];
#pragma unroll
            for (int mi = 0; mi < 2; ++mi)
                af[mi]  = *(const bf16x8*)&As[(wm * 32 + mi * 16 + lq) * LSQ + kh * 32 + quad * 8];
#pragma unroll
            for (int ni = 0; ni < 4; ++ni)
                bfg[ni] = *(const bf16x8*)&Bs[(wn * 64 + ni * 16 + lq) * LSQ + kh * 32 + quad * 8];
            if (isV) {
#pragma unroll
                for (int mi = 0; mi < 2; ++mi)
#pragma unroll
                    for (int ni = 0; ni < 4; ++ni)
                        acc[mi * 4 + ni] = __builtin_amdgcn_mfma_f32_16x16x32_bf16(
                            af[mi], bfg[ni], acc[mi * 4 + ni], 0, 0, 0);
            } else {
#pragma unroll
                for (int ni = 0; ni < 4; ++ni)
#pragma unroll
                    for (int mi = 0; mi < 2; ++mi)
                        acc[ni * 2 + mi] = __builtin_amdgcn_mfma_f32_16x16x32_bf16(
                            bfg[ni], af[mi], acc[ni * 2 + mi], 0, 0, 0);
            }
        }
    }

    if (!isV) {
#pragma unroll
        for (int ni = 0; ni < 4; ++ni) {
            int nb = n0 + wn * 64 + ni * 16 + quad * 4;
            float4 bs = *(const float4*)(bias + nb);
            int h   = (nb >> 5) & 7;
            int dh0 = nb & 31;
            bool  isQ = (nb < 256);
            float sc  = isQ ? QSCALE : 1.0f;
            ushort* dst = isQ ? qo : ko;
#pragma unroll
            for (int mi = 0; mi < 2; ++mi) {
                int m   = m0 + wm * 32 + mi * 16 + lq;
                int b   = m >> 11, seq = m & 2047;
                f32x4 c = acc[ni * 2 + mi];
                ushort4 pk;
                pk.x = f2bf((c[0] + bs.x) * sc); pk.y = f2bf((c[1] + bs.y) * sc);
                pk.z = f2bf((c[2] + bs.z) * sc); pk.w = f2bf((c[3] + bs.w) * sc);
                *(ushort4*)&dst[(((size_t)b * NH + h) * SEQ + seq) * DH + dh0] = pk;
            }
        }
    } else {
#pragma unroll
        for (int ni = 0; ni < 4; ++ni) {
            int n  = n0 + wn * 64 + ni * 16 + lq;
            int h  = (n >> 5) & 7;
            int dh = n & 31;
            float bsc = bias[n];
#pragma unroll
            for (int mi = 0; mi < 2; ++mi) {
                int mb  = m0 + wm * 32 + mi * 16 + quad * 4;
                int b   = mb >> 11, seq = mb & 2047;
                f32x4 c = acc[mi * 4 + ni];
                ushort4 pk;
                pk.x = f2bf(c[0] + bsc); pk.y = f2bf(c[1] + bsc);
                pk.z = f2bf(c[2] + bsc); pk.w = f2bf(c[3] + bsc);
                *(ushort4*)&vo[(((size_t)b * NH + h) * DH + dh) * SEQ + seq] = pk;
            }
        }
    }
}

// ---------------------------------------------------------------------------
// Kernel 2: MFMA flash attention v6 — 512-thread blocks (8 waves), 128 q per
// block (16 q/wave).  K/V staged ONCE per 128 q (r11's staging economy) with
// 4 waves/SIMD (r14's occupancy) — the two wins combined, neither cost.
// grid (16,8,4) = 512 blocks = 2 blocks/CU = 16 waves/CU.
// LDS: Ks 10.2K + VsT 8.7K + P 18.4K = 37.4 KB.
// ---------------------------------------------------------------------------
__global__ __launch_bounds__(512, 4) void attn_mfma(
    const ushort* __restrict__ qb, const ushort* __restrict__ kb,
    const ushort* __restrict__ vtb, ushort* __restrict__ a_bf)
{
    __shared__ ushort Ks[128 * KS_STRIDE];      // 10240 B
    __shared__ ushort VsT[32 * VT_STRIDE];      //  8704 B
    __shared__ ushort Pl[8 * 16 * P2_STRIDE];   // 18432 B => 37376 B total

    const int tid  = threadIdx.x;
    const int wid  = tid >> 6;          // 0..7
    const int lane = tid & 63;
    const int lq   = lane & 15;
    const int quad = lane >> 4;
    const int h    = blockIdx.y;
    const int b    = blockIdx.z;
    const int bh   = b * NH + h;
    const int q0   = blockIdx.x * 128 + wid * 16;

    const bf16x8 qf = *(const bf16x8*)(qb + ((size_t)bh * SEQ + q0 + lq) * DH + quad * 8);

    const ushort* kbase  = kb  + (size_t)bh * SEQ * DH;
    const ushort* vtbase = vtb + (size_t)bh * DH * SEQ;
    ushort* Pw = Pl + wid * 16 * P2_STRIDE;

    // staging: 512 threads, 1 uint4 chunk each for K and V
    const int kgo = (tid >> 2) * DH + (tid & 3) * 8;
    const int klo = (tid >> 2) * KS_STRIDE + (tid & 3) * 8;
    const int vgo = (tid >> 4) * SEQ + (tid & 15) * 8;
    const int vlo = (tid >> 4) * VT_STRIDE + (tid & 15) * 8;

    uint4 kr = *(const uint4*)(kbase  + kgo);
    uint4 vr = *(const uint4*)(vtbase + vgo);

    f32x4 o0  = {0.f,0.f,0.f,0.f};   // dh 0..15 (rows quad*4+reg), col q=lq
    f32x4 o1  = {0.f,0.f,0.f,0.f};   // dh 16..31
    f32x4 la0 = {0.f,0.f,0.f,0.f};   // l accumulator (ones-MFMA)
    const bf16x8 ones = {0x3F80, 0x3F80, 0x3F80, 0x3F80,
                         0x3F80, 0x3F80, 0x3F80, 0x3F80};

    for (int kt = 0; kt < SEQ; kt += 128) {
        __syncthreads();
        *(uint4*)&Ks[klo]  = kr;
        *(uint4*)&VsT[vlo] = vr;
        __syncthreads();

        {   // unconditional prefetch (wraps to 0 on last iter; value unused)
            const int ktn = (kt + 128) & (SEQ - 1);
            kr = *(const uint4*)(kbase  + (size_t)ktn * DH + kgo);
            vr = *(const uint4*)(vtbase + ktn + vgo);
        }

#pragma unroll
        for (int pass = 0; pass < 2; ++pass) {
            // ---- 4 tiles: S -> exp -> pack into P[16 x 64] ----
#pragma unroll
            for (int tt = 0; tt < 4; ++tt) {
                const int t = pass * 4 + tt;
                bf16x8 kf = *(const bf16x8*)&Ks[(t * 16 + lq) * KS_STRIDE + quad * 8];
                f32x4 z = {0.f, 0.f, 0.f, 0.f};
                f32x4 s0 = __builtin_amdgcn_mfma_f32_16x16x32_bf16(kf, qf, z, 0, 0, 0);
                uint2 w2;
                w2.x = pk2(__builtin_amdgcn_exp2f(s0[0]), __builtin_amdgcn_exp2f(s0[1]));
                w2.y = pk2(__builtin_amdgcn_exp2f(s0[2]), __builtin_amdgcn_exp2f(s0[3]));
                *(uint2*)&Pw[lq * P2_STRIDE + tt * 16 + quad * 4] = w2;
            }
            // ---- PV for this 64-col half (+ l via ones-MFMA) ----
#pragma unroll
            for (int sc = 0; sc < 2; ++sc) {
                const int vcol = pass * 64 + sc * 32;
                bf16x8 v0 = *(const bf16x8*)&VsT[lq        * VT_STRIDE + vcol + quad * 8];
                bf16x8 v1 = *(const bf16x8*)&VsT[(16 + lq) * VT_STRIDE + vcol + quad * 8];
                bf16x8 p0 = *(const bf16x8*)&Pw[lq * P2_STRIDE + sc * 32 + quad * 8];
                o0  = __builtin_amdgcn_mfma_f32_16x16x32_bf16(v0,   p0, o0,  0, 0, 0);
                o1  = __builtin_amdgcn_mfma_f32_16x16x32_bf16(v1,   p0, o1,  0, 0, 0);
                la0 = __builtin_amdgcn_mfma_f32_16x16x32_bf16(ones, p0, la0, 0, 0, 0);
            }
        }
    }

    // ---- epilogue: l = la0[0] (rows identical per col q=lq), bf16 out ----
    float inv = 1.0f / la0[0];
    ushort* dst = a_bf + ((size_t)b * SEQ + q0 + lq) * DMODEL + h * DH;
    uint2 w0, w1;
    w0.x = pk2(o0[0] * inv, o0[1] * inv);
    w0.y = pk2(o0[2] * inv, o0[3] * inv);
    w1.x = pk2(o1[0] * inv, o1[1] * inv);
    w1.y = pk2(o1[2] * inv, o1[3] * inv);
    *(uint2*)&dst[quad * 4]      = w0;
    *(uint2*)&dst[16 + quad * 4] = w1;
}

// ---------------------------------------------------------------------------
// Kernel 3: out projection, bf16 MFMA, scalar reg-prefetch. (r8/r11, proven)
// ---------------------------------------------------------------------------
__global__ __launch_bounds__(256) void out_gemm(
    const ushort* __restrict__ a, const ushort* __restrict__ wT,
    const float* __restrict__ bias, float* __restrict__ out)
{
    __shared__ ushort As[64 * LSQ];
    __shared__ ushort Bs[64 * LSQ];
    const int tid  = threadIdx.x;
    const int wid  = tid >> 6;
    const int lane = tid & 63;
    const int lq   = lane & 15;
    const int quad = lane >> 4;
    const int wm   = wid & 1;
    const int wn   = wid >> 1;
    const int m0   = blockIdx.y * 64;
    const int n0   = blockIdx.x * 64;

    const int f0 = tid, f1 = tid + 256;
    const int r0 = f0 >> 3, c0 = (f0 & 7) * 8;
    const int r1 = f1 >> 3, c1 = (f1 & 7) * 8;

    const ushort* ab = a  + (size_t)m0 * 256;
    const ushort* wb = wT + (size_t)n0 * 256;

    f32x4 acc[4];
#pragma unroll
    for (int i = 0; i < 4; ++i) acc[i] = {0.f, 0.f, 0.f, 0.f};

    uint4 ra0 = *(const uint4*)(ab + (size_t)r0 * 256 + c0);
    uint4 ra1 = *(const uint4*)(ab + (size_t)r1 * 256 + c1);
    uint4 rb0 = *(const uint4*)(wb + (size_t)r0 * 256 + c0);
    uint4 rb1 = *(const uint4*)(wb + (size_t)r1 * 256 + c1);

    for (int k0 = 0; k0 < 256; k0 += 64) {
        __syncthreads();
        *(uint4*)&As[r0 * LSQ + c0] = ra0;
        *(uint4*)&As[r1 * LSQ + c1] = ra1;
        *(uint4*)&Bs[r0 * LSQ + c0] = rb0;
        *(uint4*)&Bs[r1 * LSQ + c1] = rb1;
        __syncthreads();

        const int kn = (k0 + 64) & 255;
        ra0 = *(const uint4*)(ab + (size_t)r0 * 256 + kn + c0);
        ra1 = *(const uint4*)(ab + (size_t)r1 * 256 + kn + c1);
        rb0 = *(const uint4*)(wb + (size_t)r0 * 256 + kn + c0);
        rb1 = *(const uint4*)(wb + (size_t)r1 * 256 + kn + c1);

#pragma unroll
        for (int kh = 0; kh < 2; ++kh) {
            bf16x8 af[2], bfg[2];
#pragma unroll
            for (int mi = 0; mi < 2; ++mi)
                af[mi]  = *(const bf16x8*)&As[(wm * 32 + mi * 16 + lq) * LSQ + kh * 32 + quad * 8];
#pragma unroll
            for (int ni = 0; ni < 2; ++ni)
                bfg[ni] = *(const bf16x8*)&Bs[(wn * 32 + ni * 16 + lq) * LSQ + kh * 32 + quad * 8];
#pragma unroll
            for (int ni = 0; ni < 2; ++ni)
#pragma unroll
                for (int mi = 0; mi < 2; ++mi)
                    acc[ni * 2 + mi] = __builtin_amdgcn_mfma_f32_16x16x32_bf16(
                        bfg[ni], af[mi], acc[ni * 2 + mi], 0, 0, 0);
        }
    }

#pragma unroll
    for (int ni = 0; ni < 2; ++ni) {
        int nb = n0 + wn * 32 + ni * 16 + quad * 4;
        float4 bs = *(const float4*)(bias + nb);
#pragma unroll
        for (int mi = 0; mi < 2; ++mi) {
            int m = m0 + wm * 32 + mi * 16 + lq;
            f32x4 c = acc[ni * 2 + mi];
            float4 o;
            o.x = c[0] + bs.x; o.y = c[1] + bs.y;
            o.z = c[2] + bs.z; o.w = c[3] + bs.w;
            *(float4*)&out[(size_t)m * DMODEL + nb] = o;
        }
    }
}

extern "C" void kernel_launch(void* const* d_in, const int* in_sizes, int n_in,
                              void* d_out, int out_size, void* d_ws, size_t ws_size,
                              hipStream_t stream) {
    const float* x     = (const float*)d_in[0];
    const float* w_qkv = (const float*)d_in[1];
    const float* b_qkv = (const float*)d_in[2];
    const float* w_out = (const float*)d_in[3];
    const float* b_out = (const float*)d_in[4];
    float* out = (float*)d_out;

    const size_t TSZ = (size_t)MTOT * DMODEL;
    ushort* q_ws = (ushort*)d_ws;          // bf16 [b,h,s,dh], pre-scaled
    ushort* k_ws = q_ws + TSZ;             // bf16 [b,h,s,dh]
    ushort* v_ws = k_ws + TSZ;             // bf16 V^T [b,h,dh,s]
    ushort* a_bf = v_ws + TSZ;             // bf16 attn out [b,s,d]
    ushort* xbf  = a_bf + TSZ;             // bf16 x
    ushort* wqT  = xbf + TSZ;
    ushort* woT  = wqT + 768 * 256;

    wcvt_all<<<dim3(96, 8), 256, 0, stream>>>(w_qkv, w_out, x, wqT, woT, xbf);
    qkv_gemm<<<dim3(6, 128), 256, 0, stream>>>(xbf, wqT, b_qkv, q_ws, k_ws, v_ws);
    attn_mfma<<<dim3(16, NH, BATCH), 512, 0, stream>>>(
        q_ws, k_ws, v_ws, a_bf);
    out_gemm<<<dim3(4, 128), 256, 0, stream>>>(a_bf, woT, b_out, out);
}

// Round 16
// 120.679 us; speedup vs baseline: 1.0365x; 1.0048x over previous
//
#include <hip/hip_runtime.h>
#include <hip/hip_bf16.h>
#include <math.h>

#define BATCH  4
#define SEQ    2048
#define DMODEL 256
#define NH     8
#define DH     32
#define MTOT   (BATCH*SEQ)   // 8192
// Q is pre-scaled by 256^-0.5 * log2(e) so attention uses p = exp2(q.k) raw.
#define QSCALE 0.09016844005556021f

typedef short  bf16x8 __attribute__((ext_vector_type(8)));
typedef float  f32x4  __attribute__((ext_vector_type(4)));

static __device__ __forceinline__ ushort f2bf(float f) {
    __hip_bfloat16 h = __float2bfloat16(f);
    return __builtin_bit_cast(ushort, h);
}
// RNE-pack two fp32 -> packed bf16x2 (low = a, high = b), software fallback.
static __device__ __forceinline__ uint rne2(float a, float b) {
    uint ua = __builtin_bit_cast(uint, a);
    uint ub = __builtin_bit_cast(uint, b);
    ua += 0x7FFFu + ((ua >> 16) & 1u);
    ub += 0x7FFFu + ((ub >> 16) & 1u);
    return __builtin_amdgcn_perm(ub, ua, 0x07060302);
}
// Packed bf16 convert: HW v_cvt_pk_bf16_f32 on gfx950 (1 op) else rne2.
static __device__ __forceinline__ uint pk2(float a, float b) {
#if __has_builtin(__builtin_amdgcn_cvt_pk_bf16_f32)
    auto r = __builtin_amdgcn_cvt_pk_bf16_f32(a, b);
    return __builtin_bit_cast(uint, r);
#else
    return rne2(a, b);
#endif
}

#define LSQ 72       // qkv/out LDS row stride (64 + 8 pad), ushorts
#define KS_STRIDE 40
#define VT_STRIDE 136
#define P_STRIDE  136

// ---------------------------------------------------------------------------
// Kernel 0: weight transposes + x fp32->bf16 conversion, ONE dispatch.
// ---------------------------------------------------------------------------
__global__ __launch_bounds__(256) void wcvt_all(
    const float* __restrict__ wq, const float* __restrict__ wo,
    const float* __restrict__ x,
    ushort* __restrict__ wqT, ushort* __restrict__ woT,
    ushort* __restrict__ xbf)
{
    const int t  = threadIdx.x;
    const int bx = blockIdx.x;
    if (bx >= 32) {
        const size_t base = ((size_t)(bx - 32) * 8 + blockIdx.y) * 4096 + t * 16;
        float4 f0 = *(const float4*)(x + base);
        float4 f1 = *(const float4*)(x + base + 4);
        float4 f2 = *(const float4*)(x + base + 8);
        float4 f3 = *(const float4*)(x + base + 12);
        uint4 w0, w1;
        w0.x = pk2(f0.x, f0.y); w0.y = pk2(f0.z, f0.w);
        w0.z = pk2(f1.x, f1.y); w0.w = pk2(f1.z, f1.w);
        w1.x = pk2(f2.x, f2.y); w1.y = pk2(f2.z, f2.w);
        w1.z = pk2(f3.x, f3.y); w1.w = pk2(f3.z, f3.w);
        *(uint4*)&xbf[base]     = w0;
        *(uint4*)&xbf[base + 8] = w1;
        return;
    }
    __shared__ float T[32][33];
    const float* w; ushort* wT; int N, n0;
    if (bx < 24) { w = wq; wT = wqT; N = 768; n0 = bx * 32; }
    else         { w = wo; wT = woT; N = 256; n0 = (bx - 24) * 32; }
    const int k0 = blockIdx.y * 32;
    {
        int tr = t >> 3, tc = (t & 7) * 4;
        *(float4*)&T[tr][tc] = *(const float4*)(w + (size_t)(k0 + tr) * N + n0 + tc);
    }
    __syncthreads();
    int nl = t >> 3, kq = (t & 7) * 4;
    ushort4 pk;
    pk.x = f2bf(T[kq + 0][nl]); pk.y = f2bf(T[kq + 1][nl]);
    pk.z = f2bf(T[kq + 2][nl]); pk.w = f2bf(T[kq + 3][nl]);
    *(ushort4*)&wT[(size_t)(n0 + nl) * 256 + k0 + kq] = pk;
}

// ---------------------------------------------------------------------------
// Kernel 1: QKV projection, bf16 MFMA, scalar reg-prefetch.
// ---------------------------------------------------------------------------
__global__ __launch_bounds__(256, 3) void qkv_gemm(
    const ushort* __restrict__ xb_, const ushort* __restrict__ wT,
    const float* __restrict__ bias,
    ushort* __restrict__ qo, ushort* __restrict__ ko, ushort* __restrict__ vo)
{
    __shared__ ushort As[64 * LSQ];
    __shared__ ushort Bs[128 * LSQ];
    const int tid  = threadIdx.x;
    const int wid  = tid >> 6;
    const int lane = tid & 63;
    const int lq   = lane & 15;
    const int quad = lane >> 4;
    const int wm   = wid & 1;
    const int wn   = wid >> 1;
    const int m0   = blockIdx.y * 64;
    const int n0   = blockIdx.x * 128;
    const bool isV = (blockIdx.x >= 4);

    const int ar0 = tid >> 3,         ac0 = (tid & 7) * 8;
    const int ar1 = (tid + 256) >> 3;
    const int br0 = tid >> 3,         bc0 = (tid & 7) * 8;
    const int br1 = (tid + 256) >> 3;
    const int br2 = (tid + 512) >> 3;
    const int br3 = (tid + 768) >> 3;

    const ushort* xb = xb_ + (size_t)m0 * 256;
    const ushort* wb = wT  + (size_t)n0 * 256;

    f32x4 acc[8];
#pragma unroll
    for (int i = 0; i < 8; ++i) acc[i] = {0.f, 0.f, 0.f, 0.f};

    uint4 ra0 = *(const uint4*)(xb + (size_t)ar0 * 256 + ac0);
    uint4 ra1 = *(const uint4*)(xb + (size_t)ar1 * 256 + ac0);
    uint4 rb0 = *(const uint4*)(wb + (size_t)br0 * 256 + bc0);
    uint4 rb1 = *(const uint4*)(wb + (size_t)br1 * 256 + bc0);
    uint4 rb2 = *(const uint4*)(wb + (size_t)br2 * 256 + bc0);
    uint4 rb3 = *(const uint4*)(wb + (size_t)br3 * 256 + bc0);

    for (int k0 = 0; k0 < 256; k0 += 64) {
        __syncthreads();
        *(uint4*)&As[ar0 * LSQ + ac0] = ra0;
        *(uint4*)&As[ar1 * LSQ + ac0] = ra1;
        *(uint4*)&Bs[br0 * LSQ + bc0] = rb0;
        *(uint4*)&Bs[br1 * LSQ + bc0] = rb1;
        *(uint4*)&Bs[br2 * LSQ + bc0] = rb2;
        *(uint4*)&Bs[br3 * LSQ + bc0] = rb3;
        __syncthreads();

        const int kn = (k0 + 64) & 255;
        ra0 = *(const uint4*)(xb + (size_t)ar0 * 256 + kn + ac0);
        ra1 = *(const uint4*)(xb + (size_t)ar1 * 256 + kn + ac0);
        rb0 = *(const uint4*)(wb + (size_t)br0 * 256 + kn + bc0);
        rb1 = *(const uint4*)(wb + (size_t)br1 * 256 + kn + bc0);
        rb2 = *(const uint4*)(wb + (size_t)br2 * 256 + kn + bc0);
        rb3 = *(const uint4*)(wb + (size_t)br3 * 256 + kn + bc0);

#pragma unroll
        for (int kh = 0; kh < 2; ++kh) {
            bf16x8 af[2], bfg[4];
#pragma unroll
            for (int mi = 0; mi < 2; ++mi)
                af[mi]  = *(const bf16x8*)&As[(wm * 32 + mi * 16 + lq) * LSQ + kh * 32 + quad * 8];
#pragma unroll
            for (int ni = 0; ni < 4; ++ni)
                bfg[ni] = *(const bf16x8*)&Bs[(wn * 64 + ni * 16 + lq) * LSQ + kh * 32 + quad * 8];
            if (isV) {
#pragma unroll
                for (int mi = 0; mi < 2; ++mi)
#pragma unroll
                    for (int ni = 0; ni < 4; ++ni)
                        acc[mi * 4 + ni] = __builtin_amdgcn_mfma_f32_16x16x32_bf16(
                            af[mi], bfg[ni], acc[mi * 4 + ni], 0, 0, 0);
            } else {
#pragma unroll
                for (int ni = 0; ni < 4; ++ni)
#pragma unroll
                    for (int mi = 0; mi < 2; ++mi)
                        acc[ni * 2 + mi] = __builtin_amdgcn_mfma_f32_16x16x32_bf16(
                            bfg[ni], af[mi], acc[ni * 2 + mi], 0, 0, 0);
            }
        }
    }

    if (!isV) {
#pragma unroll
        for (int ni = 0; ni < 4; ++ni) {
            int nb = n0 + wn * 64 + ni * 16 + quad * 4;
            float4 bs = *(const float4*)(bias + nb);
            int h   = (nb >> 5) & 7;
            int dh0 = nb & 31;
            bool  isQ = (nb < 256);
            float sc  = isQ ? QSCALE : 1.0f;
            ushort* dst = isQ ? qo : ko;
#pragma unroll
            for (int mi = 0; mi < 2; ++mi) {
                int m   = m0 + wm * 32 + mi * 16 + lq;
                int b   = m >> 11, seq = m & 2047;
                f32x4 c = acc[ni * 2 + mi];
                ushort4 pk;
                pk.x = f2bf((c[0] + bs.x) * sc); pk.y = f2bf((c[1] + bs.y) * sc);
                pk.z = f2bf((c[2] + bs.z) * sc); pk.w = f2bf((c[3] + bs.w) * sc);
                *(ushort4*)&dst[(((size_t)b * NH + h) * SEQ + seq) * DH + dh0] = pk;
            }
        }
    } else {
#pragma unroll
        for (int ni = 0; ni < 4; ++ni) {
            int n  = n0 + wn * 64 + ni * 16 + lq;
            int h  = (n >> 5) & 7;
            int dh = n & 31;
            float bsc = bias[n];
#pragma unroll
            for (int mi = 0; mi < 2; ++mi) {
                int mb  = m0 + wm * 32 + mi * 16 + quad * 4;
                int b   = mb >> 11, seq = mb & 2047;
                f32x4 c = acc[mi * 4 + ni];
                ushort4 pk;
                pk.x = f2bf(c[0] + bsc); pk.y = f2bf(c[1] + bsc);
                pk.z = f2bf(c[2] + bsc); pk.w = f2bf(c[3] + bsc);
                *(ushort4*)&vo[(((size_t)b * NH + h) * DH + dh) * SEQ + seq] = pk;
            }
        }
    }
}

// ---------------------------------------------------------------------------
// Kernel 2: MFMA flash attention (r11 best).  32 q/wave, O^T form, no-max
// softmax, K-frags shared across both q-sets, HW packed bf16 cvt, l via
// ones-MFMA on packed P (quantization bias cancels in O/l).
// ---------------------------------------------------------------------------
__global__ __launch_bounds__(256, 2) void attn_mfma(
    const ushort* __restrict__ qb, const ushort* __restrict__ kb,
    const ushort* __restrict__ vtb, ushort* __restrict__ a_bf)
{
    __shared__ ushort Ks[128 * KS_STRIDE];
    __shared__ ushort VsT[32 * VT_STRIDE];
    __shared__ ushort Pl[4 * 32 * P_STRIDE];

    const int tid  = threadIdx.x;
    const int wid  = tid >> 6;
    const int lane = tid & 63;
    const int lq   = lane & 15;
    const int quad = lane >> 4;
    const int h    = blockIdx.y;
    const int b    = blockIdx.z;
    const int bh   = b * NH + h;
    const int q0   = blockIdx.x * 128 + wid * 32;

    const ushort* qbase = qb + ((size_t)bh * SEQ + q0) * DH;
    const bf16x8 qf0 = *(const bf16x8*)(qbase + (size_t)lq * DH + quad * 8);
    const bf16x8 qf1 = *(const bf16x8*)(qbase + (size_t)(16 + lq) * DH + quad * 8);

    const ushort* kbase  = kb  + (size_t)bh * SEQ * DH;
    const ushort* vtbase = vtb + (size_t)bh * DH * SEQ;
    ushort* Pw = Pl + wid * 32 * P_STRIDE;

    const int f0 = tid, f1 = tid + 256;
    const int kgo0 = (f0 >> 2) * DH + (f0 & 3) * 8;
    const int kgo1 = (f1 >> 2) * DH + (f1 & 3) * 8;
    const int klo0 = (f0 >> 2) * KS_STRIDE + (f0 & 3) * 8;
    const int klo1 = (f1 >> 2) * KS_STRIDE + (f1 & 3) * 8;
    const int vgo0 = (f0 >> 4) * SEQ + (f0 & 15) * 8;
    const int vgo1 = (f1 >> 4) * SEQ + (f1 & 15) * 8;
    const int vlo0 = (f0 >> 4) * VT_STRIDE + (f0 & 15) * 8;
    const int vlo1 = (f1 >> 4) * VT_STRIDE + (f1 & 15) * 8;

    uint4 kr0 = *(const uint4*)(kbase  + kgo0);
    uint4 kr1 = *(const uint4*)(kbase  + kgo1);
    uint4 vr0 = *(const uint4*)(vtbase + vgo0);
    uint4 vr1 = *(const uint4*)(vtbase + vgo1);

    f32x4 o0 = {0.f,0.f,0.f,0.f}, o1 = {0.f,0.f,0.f,0.f};
    f32x4 o2 = {0.f,0.f,0.f,0.f}, o3 = {0.f,0.f,0.f,0.f};
    f32x4 la0 = {0.f,0.f,0.f,0.f}, la1 = {0.f,0.f,0.f,0.f};
    const bf16x8 ones = {0x3F80, 0x3F80, 0x3F80, 0x3F80,
                         0x3F80, 0x3F80, 0x3F80, 0x3F80};  // bf16(1.0) x8

    for (int kt = 0; kt < SEQ; kt += 128) {
        __syncthreads();
        *(uint4*)&Ks[klo0]  = kr0;
        *(uint4*)&Ks[klo1]  = kr1;
        *(uint4*)&VsT[vlo0] = vr0;
        *(uint4*)&VsT[vlo1] = vr1;
        __syncthreads();

        {   // unconditional prefetch (wraps to 0 on last iter; value unused)
            const int ktn = (kt + 128) & (SEQ - 1);
            const ushort* kn = kbase  + (size_t)ktn * DH;
            const ushort* vn = vtbase + ktn;
            kr0 = *(const uint4*)(kn + kgo0);
            kr1 = *(const uint4*)(kn + kgo1);
            vr0 = *(const uint4*)(vn + vgo0);
            vr1 = *(const uint4*)(vn + vgo1);
        }

        // ---- S^T tiles, both q-sets per kf load ----
        f32x4 st0[8], st1[8];
#pragma unroll
        for (int t = 0; t < 8; ++t) {
            bf16x8 kf = *(const bf16x8*)&Ks[(t * 16 + lq) * KS_STRIDE + quad * 8];
            f32x4 z = {0.f, 0.f, 0.f, 0.f};
            st0[t] = __builtin_amdgcn_mfma_f32_16x16x32_bf16(kf, qf0, z, 0, 0, 0);
            st1[t] = __builtin_amdgcn_mfma_f32_16x16x32_bf16(kf, qf1, z, 0, 0, 0);
        }

        // ---- p = exp2(s), packed bf16 into P ----
#pragma unroll
        for (int t = 0; t < 8; ++t) {
            uint2 w2;
            w2.x = pk2(__builtin_amdgcn_exp2f(st0[t][0]),
                       __builtin_amdgcn_exp2f(st0[t][1]));
            w2.y = pk2(__builtin_amdgcn_exp2f(st0[t][2]),
                       __builtin_amdgcn_exp2f(st0[t][3]));
            *(uint2*)&Pw[lq * P_STRIDE + t * 16 + quad * 4] = w2;
        }
#pragma unroll
        for (int t = 0; t < 8; ++t) {
            uint2 w2;
            w2.x = pk2(__builtin_amdgcn_exp2f(st1[t][0]),
                       __builtin_amdgcn_exp2f(st1[t][1]));
            w2.y = pk2(__builtin_amdgcn_exp2f(st1[t][2]),
                       __builtin_amdgcn_exp2f(st1[t][3]));
            *(uint2*)&Pw[(16 + lq) * P_STRIDE + t * 16 + quad * 4] = w2;
        }

        // ---- PV (O^T) + l via ones-MFMA; V-frags shared across q-sets ----
#pragma unroll
        for (int s = 0; s < 4; ++s) {
            bf16x8 v0 = *(const bf16x8*)&VsT[lq        * VT_STRIDE + s * 32 + quad * 8];
            bf16x8 v1 = *(const bf16x8*)&VsT[(16 + lq) * VT_STRIDE + s * 32 + quad * 8];
            bf16x8 p0 = *(const bf16x8*)&Pw[lq        * P_STRIDE + s * 32 + quad * 8];
            bf16x8 p1 = *(const bf16x8*)&Pw[(16 + lq) * P_STRIDE + s * 32 + quad * 8];
            o0  = __builtin_amdgcn_mfma_f32_16x16x32_bf16(v0,   p0, o0,  0, 0, 0);
            o1  = __builtin_amdgcn_mfma_f32_16x16x32_bf16(v1,   p0, o1,  0, 0, 0);
            o2  = __builtin_amdgcn_mfma_f32_16x16x32_bf16(v0,   p1, o2,  0, 0, 0);
            o3  = __builtin_amdgcn_mfma_f32_16x16x32_bf16(v1,   p1, o3,  0, 0, 0);
            la0 = __builtin_amdgcn_mfma_f32_16x16x32_bf16(ones, p0, la0, 0, 0, 0);
            la1 = __builtin_amdgcn_mfma_f32_16x16x32_bf16(ones, p1, la1, 0, 0, 0);
        }
    }

    float inv0 = 1.0f / la0[0];
    float inv1 = 1.0f / la1[0];
    ushort* dst0 = a_bf + ((size_t)b * SEQ + q0 + lq) * DMODEL + h * DH;
    ushort* dst1 = dst0 + 16 * DMODEL;
    uint2 w0, w1;
    w0.x = pk2(o0[0] * inv0, o0[1] * inv0);
    w0.y = pk2(o0[2] * inv0, o0[3] * inv0);
    w1.x = pk2(o1[0] * inv0, o1[1] * inv0);
    w1.y = pk2(o1[2] * inv0, o1[3] * inv0);
    *(uint2*)&dst0[quad * 4]      = w0;
    *(uint2*)&dst0[16 + quad * 4] = w1;
    w0.x = pk2(o2[0] * inv1, o2[1] * inv1);
    w0.y = pk2(o2[2] * inv1, o2[3] * inv1);
    w1.x = pk2(o3[0] * inv1, o3[1] * inv1);
    w1.y = pk2(o3[2] * inv1, o3[3] * inv1);
    *(uint2*)&dst1[quad * 4]      = w0;
    *(uint2*)&dst1[16 + quad * 4] = w1;
}

// ---------------------------------------------------------------------------
// Kernel 3: out projection, bf16 MFMA, scalar reg-prefetch.
// ---------------------------------------------------------------------------
__global__ __launch_bounds__(256) void out_gemm(
    const ushort* __restrict__ a, const ushort* __restrict__ wT,
    const float* __restrict__ bias, float* __restrict__ out)
{
    __shared__ ushort As[64 * LSQ];
    __shared__ ushort Bs[64 * LSQ];
    const int tid  = threadIdx.x;
    const int wid  = tid >> 6;
    const int lane = tid & 63;
    const int lq   = lane & 15;
    const int quad = lane >> 4;
    const int wm   = wid & 1;
    const int wn   = wid >> 1;
    const int m0   = blockIdx.y * 64;
    const int n0   = blockIdx.x * 64;

    const int f0 = tid, f1 = tid + 256;
    const int r0 = f0 >> 3, c0 = (f0 & 7) * 8;
    const int r1 = f1 >> 3, c1 = (f1 & 7) * 8;

    const ushort* ab = a  + (size_t)m0 * 256;
    const ushort* wb = wT + (size_t)n0 * 256;

    f32x4 acc[4];
#pragma unroll
    for (int i = 0; i < 4; ++i) acc[i] = {0.f, 0.f, 0.f, 0.f};

    uint4 ra0 = *(const uint4*)(ab + (size_t)r0 * 256 + c0);
    uint4 ra1 = *(const uint4*)(ab + (size_t)r1 * 256 + c1);
    uint4 rb0 = *(const uint4*)(wb + (size_t)r0 * 256 + c0);
    uint4 rb1 = *(const uint4*)(wb + (size_t)r1 * 256 + c1);

    for (int k0 = 0; k0 < 256; k0 += 64) {
        __syncthreads();
        *(uint4*)&As[r0 * LSQ + c0] = ra0;
        *(uint4*)&As[r1 * LSQ + c1] = ra1;
        *(uint4*)&Bs[r0 * LSQ + c0] = rb0;
        *(uint4*)&Bs[r1 * LSQ + c1] = rb1;
        __syncthreads();

        const int kn = (k0 + 64) & 255;
        ra0 = *(const uint4*)(ab + (size_t)r0 * 256 + kn + c0);
        ra1 = *(const uint4*)(ab + (size_t)r1 * 256 + kn + c1);
        rb0 = *(const uint4*)(wb + (size_t)r0 * 256 + kn + c0);
        rb1 = *(const uint4*)(wb + (size_t)r1 * 256 + kn + c1);

#pragma unroll
        for (int kh = 0; kh < 2; ++kh) {
            bf16x8 af[2], bfg[2];
#pragma unroll
            for (int mi = 0; mi < 2; ++mi)
                af[mi]  = *(const bf16x8*)&As[(wm * 32 + mi * 16 + lq) * LSQ + kh * 32 + quad * 8];
#pragma unroll
            for (int ni = 0; ni < 2; ++ni)
                bfg[ni] = *(const bf16x8*)&Bs[(wn * 32 + ni * 16 + lq) * LSQ + kh * 32 + quad * 8];
#pragma unroll
            for (int ni = 0; ni < 2; ++ni)
#pragma unroll
                for (int mi = 0; mi < 2; ++mi)
                    acc[ni * 2 + mi] = __builtin_amdgcn_mfma_f32_16x16x32_bf16(
                        bfg[ni], af[mi], acc[ni * 2 + mi], 0, 0, 0);
        }
    }

#pragma unroll
    for (int ni = 0; ni < 2; ++ni) {
        int nb = n0 + wn * 32 + ni * 16 + quad * 4;
        float4 bs = *(const float4*)(bias + nb);
#pragma unroll
        for (int mi = 0; mi < 2; ++mi) {
            int m = m0 + wm * 32 + mi * 16 + lq;
            f32x4 c = acc[ni * 2 + mi];
            float4 o;
            o.x = c[0] + bs.x; o.y = c[1] + bs.y;
            o.z = c[2] + bs.z; o.w = c[3] + bs.w;
            *(float4*)&out[(size_t)m * DMODEL + nb] = o;
        }
    }
}

extern "C" void kernel_launch(void* const* d_in, const int* in_sizes, int n_in,
                              void* d_out, int out_size, void* d_ws, size_t ws_size,
                              hipStream_t stream) {
    const float* x     = (const float*)d_in[0];
    const float* w_qkv = (const float*)d_in[1];
    const float* b_qkv = (const float*)d_in[2];
    const float* w_out = (const float*)d_in[3];
    const float* b_out = (const float*)d_in[4];
    float* out = (float*)d_out;

    const size_t TSZ = (size_t)MTOT * DMODEL;
    ushort* q_ws = (ushort*)d_ws;          // Q pre-scaled bf16 [b,h,s,dh]
    ushort* k_ws = q_ws + TSZ;             // K bf16 [b,h,s,dh]
    ushort* v_ws = k_ws + TSZ;             // V^T bf16 [b,h,dh,s]
    ushort* a_bf = v_ws + TSZ;             // attn out bf16 [b,s,d]
    ushort* xbf  = a_bf + TSZ;             // x bf16
    ushort* wqT  = xbf + TSZ;
    ushort* woT  = wqT + 768 * 256;

    wcvt_all<<<dim3(96, 8), 256, 0, stream>>>(w_qkv, w_out, x, wqT, woT, xbf);
    qkv_gemm<<<dim3(6, 128), 256, 0, stream>>>(xbf, wqT, b_qkv, q_ws, k_ws, v_ws);
    attn_mfma<<<dim3(SEQ / 128, NH, BATCH), 256, 0, stream>>>(
        q_ws, k_ws, v_ws, a_bf);
    out_gemm<<<dim3(4, 128), 256, 0, stream>>>(a_bf, woT, b_out, out);
}